// Round 4
// baseline (106.273 us; speedup 1.0000x reference)
//
#include <hip/hip_runtime.h>

// SqueezeSeg recurrent CRF, MI355X (gfx950). Single-kernel halo-redundant fusion,
// 3 CRF iterations per block over nested shrinking regions (12x72 -> 10x68 ->
// 8x64 around the owned 8x64 tile). Fixed thread->pixel-pair mapping (512-thread
// blocks, one pass per step). This revision:
//  (1) filt loads issued BEFORE phase 0 -> 50 MB filt fetch overlaps the
//      x/mask fetch + softmax + LDS-write phase (vmcnt wait lands post-barrier).
//  (2) fm[k] = f[k]*mask_neighbor precomputed once (in place, zero extra VGPR):
//      mask LDS reads and f*m muls vanish from all 3 steps.
//  (3) separable Gaussian (G2=G1^2, G5=G1*G4): column-strip colv = Uc+G1*(Um+Up),
//      A = sum GA[t]*colv[t] - ucen, GA=(G4,G1,1,G1,G4). Fewer FMAs, low VGPR.
// g_ang == g_bi (theta=0.9 both) -> ang == bi_ang.
// compat = (1-I)*coef -> out[o] = coef*(sum_c v[c] - v[o]).

#define NCLASS 4
#define HH 64
#define WW 512
#define BB 16
#define TH 8
#define TW 64
#define UR (TH + 6)     // 14 rows:  tile + 3 halo each side
#define UC (TW + 12)    // 76 cols:  tile + 6 halo each side
#define PLANE (HH * WW)
#define R1H 12          // step-1 region rows
#define R1W 72          // step-1 region cols
#define GPR1 (R1W / 2)  // 36 pixel-pairs per region row
#define NPAIR1 (R1H * GPR1)  // 432 pairs, one per thread

// exp(-d2 / (2*0.9^2)) for d2 = 1,2,4,5 ; separable: G2=G1*G1, G5=G1*G4
#define G1 0.53940412f
#define G2 0.29095687f
#define G4 0.08466190f
#define G5 0.04566227f

__device__ __forceinline__ void fma4(float4& d, float s, const float4& v) {
    d.x = fmaf(s, v.x, d.x);
    d.y = fmaf(s, v.y, d.y);
    d.z = fmaf(s, v.z, d.z);
    d.w = fmaf(s, v.w, d.w);
}

// combine ang/bilateral accumulators into the new x (optionally softmaxed)
template <bool SM>
__device__ __forceinline__ float4 crf_combine(const float4 A, const float4 C,
                                              const float4 u, const float mcen)
{
    const float bx = C.x * mcen * A.x;
    const float by = C.y * mcen * A.y;
    const float bz = C.z * mcen * A.z;
    const float bw = C.w * mcen * A.w;
    const float sa = A.x + A.y + A.z + A.w;
    const float sb = bx + by + bz + bw;
    float4 r;
    r.x = u.x + 0.02f * (sa - A.x) + 0.1f * (sb - bx);
    r.y = u.y + 0.02f * (sa - A.y) + 0.1f * (sb - by);
    r.z = u.z + 0.02f * (sa - A.z) + 0.1f * (sb - bz);
    r.w = u.w + 0.02f * (sa - A.w) + 0.1f * (sb - bw);
    if (SM) {
        const float mx  = fmaxf(fmaxf(r.x, r.y), fmaxf(r.z, r.w));
        const float e0  = __expf(r.x - mx);
        const float e1  = __expf(r.y - mx);
        const float e2  = __expf(r.z - mx);
        const float e3  = __expf(r.w - mx);
        const float inv = 1.0f / (e0 + e1 + e2 + e3);
        r = make_float4(e0 * inv, e1 * inv, e2 * inv, e3 * inv);
    }
    return r;
}

// One CRF step for this thread's FIXED pixel pair. fm[14] = filt*mask_neighbor
// (step-invariant, precomputed). Column-strip walk: only one 3-row column of U
// live at a time. MR/MC: halo margin of the region this step computes.
template <int MR, int MC, bool FINAL>
__device__ __forceinline__ void crf_step(
    float4 (*__restrict__ u_lds)[UC],
    const float2* __restrict__ fm, float mcen0, float mcen1,
    float* __restrict__ dst,
    int b, int lr1, int lc1, int gh, int gw, bool inb)
{
    constexpr int RH = TH + 2 * MR;
    constexpr int RW = TW + 2 * MC;
    // this step's region, expressed in step-1 coordinates (nested subsets)
    constexpr int LR_LO = 2 - MR, LR_HI = 2 - MR + RH;
    constexpr int LC_LO = 4 - MC, LC_HI = 4 - MC + RW;

    const bool act = inb && lr1 >= LR_LO && lr1 < LR_HI
                         && lc1 >= LC_LO && (lc1 + 1) < LC_HI;

    // ga(da) for da = t-2 (separable horizontal weights, center included)
    const float GA[5] = {G4, G1, 1.0f, G1, G4};

    float4 r0 = make_float4(0.f, 0.f, 0.f, 0.f);
    float4 r1 = r0;

    if (act) {
        const int ur = lr1 + 1;   // u_lds row of this pair
        const int uc = lc1 + 2;   // u_lds col of first pixel (even)

        float4 A0 = make_float4(0.f, 0.f, 0.f, 0.f);
        float4 A1 = A0, C0 = A0, C1 = A0;
        float4 ucen0 = A0, ucen1 = A0;

#pragma unroll
        for (int t = 0; t < 6; ++t) {
            const float4 Um = u_lds[ur - 1][uc - 2 + t];
            const float4 Uc = u_lds[ur    ][uc - 2 + t];
            const float4 Up = u_lds[ur + 1][uc - 2 + t];
            // separable vertical sum: colv = Uc + G1*(Um+Up)
            float4 cv;
            cv.x = fmaf(G1, Um.x + Up.x, Uc.x);
            cv.y = fmaf(G1, Um.y + Up.y, Uc.y);
            cv.z = fmaf(G1, Um.z + Up.z, Uc.z);
            cv.w = fmaf(G1, Um.w + Up.w, Uc.w);
            if (t == 2) ucen0 = Uc;
            if (t == 3) ucen1 = Uc;
            if (t < 5)  fma4(A0, GA[t],     cv);
            if (t >= 1) fma4(A1, GA[t - 1], cv);
            // bilateral: fm-weighted, tap-indexed (dz-major k like filt layout)
            if (t < 5) {
                fma4(C0, fm[t].x,     Um);           // dz=-1, k=t
                fma4(C0, fm[9 + t].x, Up);           // dz=+1, k=9+t
                if (t != 2) {
                    const int kc = 5 + (t > 2 ? t - 1 : t);
                    fma4(C0, fm[kc].x, Uc);          // dz=0 (center excluded)
                }
            }
            if (t >= 1) {
                const int t1 = t - 1;
                fma4(C1, fm[t1].y,     Um);
                fma4(C1, fm[9 + t1].y, Up);
                if (t1 != 2) {
                    const int kc = 5 + (t1 > 2 ? t1 - 1 : t1);
                    fma4(C1, fm[kc].y, Uc);
                }
            }
        }
        // remove center term (weight gz(0)*ga(0) = 1)
        A0.x -= ucen0.x; A0.y -= ucen0.y; A0.z -= ucen0.z; A0.w -= ucen0.w;
        A1.x -= ucen1.x; A1.y -= ucen1.y; A1.z -= ucen1.z; A1.w -= ucen1.w;

        r0 = crf_combine<!FINAL>(A0, C0, ucen0, mcen0);
        r1 = crf_combine<!FINAL>(A1, C1, ucen1, mcen1);

        if (FINAL) {
            float* o = dst + ((size_t)b * NCLASS * HH + gh) * WW + gw;
            *reinterpret_cast<float2*>(o)             = make_float2(r0.x, r1.x);
            *reinterpret_cast<float2*>(o + PLANE)     = make_float2(r0.y, r1.y);
            *reinterpret_cast<float2*>(o + 2 * PLANE) = make_float2(r0.z, r1.z);
            *reinterpret_cast<float2*>(o + 3 * PLANE) = make_float2(r0.w, r1.w);
        }
    }

    if (!FINAL) {
        __syncthreads();   // all reads of u_t done before overwrite
        if (act) {
            u_lds[lr1 + 1][lc1 + 2] = r0;
            u_lds[lr1 + 1][lc1 + 3] = r1;
        }
        // global-OOB entries inside the region were 0 from phase 0 and are
        // never rewritten -> stay 0, matching zero-pad gather semantics.
        __syncthreads();   // u_{t+1} visible before next step's reads
    }
}

__global__ __launch_bounds__(512, 4) void crf_fused(
    const float* __restrict__ xin,   // [B,4,H,W]
    const float* __restrict__ filt,  // [B,1,14,H,W]
    const float* __restrict__ mask,  // [B,1,H,W]
    float* __restrict__ xout)        // [B,4,H,W]
{
    __shared__ float4 u_lds[UR][UC];  // class-packed unary, 17.0 KB
    __shared__ float  m_lds[UR][UC];  // mask, 4.3 KB

    const int b   = blockIdx.z;
    const int h0  = blockIdx.y * TH;
    const int w0  = blockIdx.x * TW;
    const int tid = threadIdx.x;

    // ---- fixed thread -> pixel-pair mapping over the step-1 region ----
    const int  p   = tid;                    // pair id (0..431 active)
    const int  lr1 = p / GPR1;               // region row
    const int  lc1 = 2 * (p - lr1 * GPR1);   // region col of first pixel (even)
    const int  gh  = h0 + lr1 - 2;
    const int  gw  = w0 + lc1 - 4;
    const bool inb = (p < NPAIR1) && gh >= 0 && gh < HH && gw >= 0 && gw < WW;

    // ---- filt taps: issue loads FIRST so the fetch overlaps phase 0 ----
    float2 f[14];
    if (inb) {
        const float* fp = filt + ((size_t)b * 14 * HH + gh) * WW + gw;
#pragma unroll
        for (int k = 0; k < 14; ++k)
            f[k] = *reinterpret_cast<const float2*>(fp + (size_t)k * PLANE);
    }

    // ---- phase 0: softmax(x) + mask over the full 14x76 patch, pixel pairs ----
    constexpr int NP = (UR * UC) / 2;   // 532 pairs
    for (int idx = tid; idx < NP; idx += 512) {
        const int lr = idx / (UC / 2);
        const int lc = 2 * (idx - lr * (UC / 2));
        const int ph = h0 + lr - 3;
        const int pw = w0 + lc - 6;     // even -> pair never straddles 0/W
        float4 u0 = make_float4(0.f, 0.f, 0.f, 0.f);
        float4 u1 = u0;
        float2 mm = make_float2(0.f, 0.f);
        if (ph >= 0 && ph < HH && pw >= 0 && pw < WW) {
            const float* px = xin + ((size_t)b * NCLASS * HH + ph) * WW + pw;
            const float2 v0 = *reinterpret_cast<const float2*>(px);
            const float2 v1 = *reinterpret_cast<const float2*>(px + PLANE);
            const float2 v2 = *reinterpret_cast<const float2*>(px + 2 * PLANE);
            const float2 v3 = *reinterpret_cast<const float2*>(px + 3 * PLANE);
            mm = *reinterpret_cast<const float2*>(mask + ((size_t)b * HH + ph) * WW + pw);
            {
                const float mx  = fmaxf(fmaxf(v0.x, v1.x), fmaxf(v2.x, v3.x));
                const float e0  = __expf(v0.x - mx);
                const float e1  = __expf(v1.x - mx);
                const float e2  = __expf(v2.x - mx);
                const float e3  = __expf(v3.x - mx);
                const float inv = 1.0f / (e0 + e1 + e2 + e3);
                u0 = make_float4(e0 * inv, e1 * inv, e2 * inv, e3 * inv);
            }
            {
                const float mx  = fmaxf(fmaxf(v0.y, v1.y), fmaxf(v2.y, v3.y));
                const float e0  = __expf(v0.y - mx);
                const float e1  = __expf(v1.y - mx);
                const float e2  = __expf(v2.y - mx);
                const float e3  = __expf(v3.y - mx);
                const float inv = 1.0f / (e0 + e1 + e2 + e3);
                u1 = make_float4(e0 * inv, e1 * inv, e2 * inv, e3 * inv);
            }
        }
        u_lds[lr][lc]     = u0;
        u_lds[lr][lc + 1] = u1;
        *reinterpret_cast<float2*>(&m_lds[lr][lc]) = mm;
    }
    __syncthreads();

    // ---- fold mask into filt: fm[k] = f[k] * m_neighbor (step-invariant) ----
    float mcen0 = 0.f, mcen1 = 0.f;
    if (inb) {
        const int ur = lr1 + 1;
        const int uc = lc1 + 2;
        mcen0 = m_lds[ur][uc];
        mcen1 = m_lds[ur][uc + 1];
#pragma unroll
        for (int dz = -1; dz <= 1; ++dz) {
            const int rr = ur + dz;
            float M[6];
#pragma unroll
            for (int t3 = 0; t3 < 3; ++t3) {
                const float2 mm =
                    *reinterpret_cast<const float2*>(&m_lds[rr][uc - 2 + 2 * t3]);
                M[2 * t3]     = mm.x;
                M[2 * t3 + 1] = mm.y;
            }
#pragma unroll
            for (int t = 0; t < 5; ++t) {
                if (dz == 0 && t == 2) continue;
                const int k = (dz == -1) ? t
                            : (dz == 0)  ? 5 + (t > 2 ? t - 1 : t)
                                         : 9 + t;
                f[k].x *= M[t];
                f[k].y *= M[t + 1];
            }
        }
    }

    crf_step<2, 4, false>(u_lds, f, mcen0, mcen1, xout, b, lr1, lc1, gh, gw, inb);
    crf_step<1, 2, false>(u_lds, f, mcen0, mcen1, xout, b, lr1, lc1, gh, gw, inb);
    crf_step<0, 0, true >(u_lds, f, mcen0, mcen1, xout, b, lr1, lc1, gh, gw, inb);
}

extern "C" void kernel_launch(void* const* d_in, const int* in_sizes, int n_in,
                              void* d_out, int out_size, void* d_ws, size_t ws_size,
                              hipStream_t stream) {
    const float* x    = (const float*)d_in[0];  // [16,4,64,512]
    const float* filt = (const float*)d_in[1];  // [16,1,14,64,512]
    const float* msk  = (const float*)d_in[2];  // [16,1,64,512]
    float* out = (float*)d_out;
    (void)d_ws; (void)ws_size;

    dim3 grid(WW / TW, HH / TH, BB);   // (8, 8, 16) = 1024 blocks
    dim3 block(512);
    crf_fused<<<grid, block, 0, stream>>>(x, filt, msk, out);
}

// Round 5
// 105.032 us; speedup vs baseline: 1.0118x; 1.0118x over previous
//
#include <hip/hip_runtime.h>

// SqueezeSeg recurrent CRF, MI355X (gfx950). Single-kernel halo-redundant fusion,
// 3 CRF iterations per block over nested shrinking regions (12x72 -> 10x68 ->
// 8x64 around the owned 8x64 tile). Fixed thread->pixel-pair mapping (512-thread
// blocks, one pass per step). Revision notes:
//  - filt loads are issued AFTER the phase-0 barrier (round-4 moved them before
//    phase 0 and regressed +10us: vmcnt is in-order, so every phase-0 load-use
//    had to drain the whole cold filt burst first. Do not re-order them.)
//  - fm[k] = f[k]*mask_neighbor folded once (in place): no mask LDS reads or
//    f*m muls inside the 3 steps.
//  - separable Gaussian (G2=G1^2, G5=G1*G4): colv = Uc+G1*(Um+Up), then
//    A = sum GA[t]*colv[t] - ucen with GA=(G4,G1,1,G1,G4).
// g_ang == g_bi (theta=0.9 both) -> ang == bi_ang.
// compat = (1-I)*coef -> out[o] = coef*(sum_c v[c] - v[o]).

#define NCLASS 4
#define HH 64
#define WW 512
#define BB 16
#define TH 8
#define TW 64
#define UR (TH + 6)     // 14 rows:  tile + 3 halo each side
#define UC (TW + 12)    // 76 cols:  tile + 6 halo each side
#define PLANE (HH * WW)
#define R1H 12          // step-1 region rows
#define R1W 72          // step-1 region cols
#define GPR1 (R1W / 2)  // 36 pixel-pairs per region row
#define NPAIR1 (R1H * GPR1)  // 432 pairs, one per thread

// exp(-d2 / (2*0.9^2)) for d2 = 1,2,4,5 ; separable: G2=G1*G1, G5=G1*G4
#define G1 0.53940412f
#define G2 0.29095687f
#define G4 0.08466190f
#define G5 0.04566227f

__device__ __forceinline__ void fma4(float4& d, float s, const float4& v) {
    d.x = fmaf(s, v.x, d.x);
    d.y = fmaf(s, v.y, d.y);
    d.z = fmaf(s, v.z, d.z);
    d.w = fmaf(s, v.w, d.w);
}

// combine ang/bilateral accumulators into the new x (optionally softmaxed)
template <bool SM>
__device__ __forceinline__ float4 crf_combine(const float4 A, const float4 C,
                                              const float4 u, const float mcen)
{
    const float bx = C.x * mcen * A.x;
    const float by = C.y * mcen * A.y;
    const float bz = C.z * mcen * A.z;
    const float bw = C.w * mcen * A.w;
    const float sa = A.x + A.y + A.z + A.w;
    const float sb = bx + by + bz + bw;
    float4 r;
    r.x = u.x + 0.02f * (sa - A.x) + 0.1f * (sb - bx);
    r.y = u.y + 0.02f * (sa - A.y) + 0.1f * (sb - by);
    r.z = u.z + 0.02f * (sa - A.z) + 0.1f * (sb - bz);
    r.w = u.w + 0.02f * (sa - A.w) + 0.1f * (sb - bw);
    if (SM) {
        const float mx  = fmaxf(fmaxf(r.x, r.y), fmaxf(r.z, r.w));
        const float e0  = __expf(r.x - mx);
        const float e1  = __expf(r.y - mx);
        const float e2  = __expf(r.z - mx);
        const float e3  = __expf(r.w - mx);
        const float inv = 1.0f / (e0 + e1 + e2 + e3);
        r = make_float4(e0 * inv, e1 * inv, e2 * inv, e3 * inv);
    }
    return r;
}

// One CRF step for this thread's FIXED pixel pair. fm[14] = filt*mask_neighbor
// (step-invariant, precomputed). Column-strip walk: only one 3-row column of U
// live at a time. MR/MC: halo margin of the region this step computes.
template <int MR, int MC, bool FINAL>
__device__ __forceinline__ void crf_step(
    float4 (*__restrict__ u_lds)[UC],
    const float2* __restrict__ fm, float mcen0, float mcen1,
    float* __restrict__ dst,
    int b, int lr1, int lc1, int gh, int gw, bool inb)
{
    constexpr int RH = TH + 2 * MR;
    constexpr int RW = TW + 2 * MC;
    // this step's region, expressed in step-1 coordinates (nested subsets)
    constexpr int LR_LO = 2 - MR, LR_HI = 2 - MR + RH;
    constexpr int LC_LO = 4 - MC, LC_HI = 4 - MC + RW;

    const bool act = inb && lr1 >= LR_LO && lr1 < LR_HI
                         && lc1 >= LC_LO && (lc1 + 1) < LC_HI;

    // ga(da) for da = t-2 (separable horizontal weights, center included)
    const float GA[5] = {G4, G1, 1.0f, G1, G4};

    float4 r0 = make_float4(0.f, 0.f, 0.f, 0.f);
    float4 r1 = r0;

    if (act) {
        const int ur = lr1 + 1;   // u_lds row of this pair
        const int uc = lc1 + 2;   // u_lds col of first pixel (even)

        float4 A0 = make_float4(0.f, 0.f, 0.f, 0.f);
        float4 A1 = A0, C0 = A0, C1 = A0;
        float4 ucen0 = A0, ucen1 = A0;

#pragma unroll
        for (int t = 0; t < 6; ++t) {
            const float4 Um = u_lds[ur - 1][uc - 2 + t];
            const float4 Uc = u_lds[ur    ][uc - 2 + t];
            const float4 Up = u_lds[ur + 1][uc - 2 + t];
            // separable vertical sum: colv = Uc + G1*(Um+Up)
            float4 cv;
            cv.x = fmaf(G1, Um.x + Up.x, Uc.x);
            cv.y = fmaf(G1, Um.y + Up.y, Uc.y);
            cv.z = fmaf(G1, Um.z + Up.z, Uc.z);
            cv.w = fmaf(G1, Um.w + Up.w, Uc.w);
            if (t == 2) ucen0 = Uc;
            if (t == 3) ucen1 = Uc;
            if (t < 5)  fma4(A0, GA[t],     cv);
            if (t >= 1) fma4(A1, GA[t - 1], cv);
            // bilateral: fm-weighted, tap-indexed (dz-major k like filt layout)
            if (t < 5) {
                fma4(C0, fm[t].x,     Um);           // dz=-1, k=t
                fma4(C0, fm[9 + t].x, Up);           // dz=+1, k=9+t
                if (t != 2) {
                    const int kc = 5 + (t > 2 ? t - 1 : t);
                    fma4(C0, fm[kc].x, Uc);          // dz=0 (center excluded)
                }
            }
            if (t >= 1) {
                const int t1 = t - 1;
                fma4(C1, fm[t1].y,     Um);
                fma4(C1, fm[9 + t1].y, Up);
                if (t1 != 2) {
                    const int kc = 5 + (t1 > 2 ? t1 - 1 : t1);
                    fma4(C1, fm[kc].y, Uc);
                }
            }
        }
        // remove center term (weight gz(0)*ga(0) = 1)
        A0.x -= ucen0.x; A0.y -= ucen0.y; A0.z -= ucen0.z; A0.w -= ucen0.w;
        A1.x -= ucen1.x; A1.y -= ucen1.y; A1.z -= ucen1.z; A1.w -= ucen1.w;

        r0 = crf_combine<!FINAL>(A0, C0, ucen0, mcen0);
        r1 = crf_combine<!FINAL>(A1, C1, ucen1, mcen1);

        if (FINAL) {
            float* o = dst + ((size_t)b * NCLASS * HH + gh) * WW + gw;
            *reinterpret_cast<float2*>(o)             = make_float2(r0.x, r1.x);
            *reinterpret_cast<float2*>(o + PLANE)     = make_float2(r0.y, r1.y);
            *reinterpret_cast<float2*>(o + 2 * PLANE) = make_float2(r0.z, r1.z);
            *reinterpret_cast<float2*>(o + 3 * PLANE) = make_float2(r0.w, r1.w);
        }
    }

    if (!FINAL) {
        __syncthreads();   // all reads of u_t done before overwrite
        if (act) {
            u_lds[lr1 + 1][lc1 + 2] = r0;
            u_lds[lr1 + 1][lc1 + 3] = r1;
        }
        // global-OOB entries inside the region were 0 from phase 0 and are
        // never rewritten -> stay 0, matching zero-pad gather semantics.
        __syncthreads();   // u_{t+1} visible before next step's reads
    }
}

__global__ __launch_bounds__(512, 4) void crf_fused(
    const float* __restrict__ xin,   // [B,4,H,W]
    const float* __restrict__ filt,  // [B,1,14,H,W]
    const float* __restrict__ mask,  // [B,1,H,W]
    float* __restrict__ xout)        // [B,4,H,W]
{
    __shared__ float4 u_lds[UR][UC];  // class-packed unary, 17.0 KB
    __shared__ float  m_lds[UR][UC];  // mask, 4.3 KB

    const int b   = blockIdx.z;
    const int h0  = blockIdx.y * TH;
    const int w0  = blockIdx.x * TW;
    const int tid = threadIdx.x;

    // ---- phase 0: softmax(x) + mask over the full 14x76 patch, pixel pairs ----
    constexpr int NP = (UR * UC) / 2;   // 532 pairs
    for (int idx = tid; idx < NP; idx += 512) {
        const int lr = idx / (UC / 2);
        const int lc = 2 * (idx - lr * (UC / 2));
        const int ph = h0 + lr - 3;
        const int pw = w0 + lc - 6;     // even -> pair never straddles 0/W
        float4 u0 = make_float4(0.f, 0.f, 0.f, 0.f);
        float4 u1 = u0;
        float2 mm = make_float2(0.f, 0.f);
        if (ph >= 0 && ph < HH && pw >= 0 && pw < WW) {
            const float* px = xin + ((size_t)b * NCLASS * HH + ph) * WW + pw;
            const float2 v0 = *reinterpret_cast<const float2*>(px);
            const float2 v1 = *reinterpret_cast<const float2*>(px + PLANE);
            const float2 v2 = *reinterpret_cast<const float2*>(px + 2 * PLANE);
            const float2 v3 = *reinterpret_cast<const float2*>(px + 3 * PLANE);
            mm = *reinterpret_cast<const float2*>(mask + ((size_t)b * HH + ph) * WW + pw);
            {
                const float mx  = fmaxf(fmaxf(v0.x, v1.x), fmaxf(v2.x, v3.x));
                const float e0  = __expf(v0.x - mx);
                const float e1  = __expf(v1.x - mx);
                const float e2  = __expf(v2.x - mx);
                const float e3  = __expf(v3.x - mx);
                const float inv = 1.0f / (e0 + e1 + e2 + e3);
                u0 = make_float4(e0 * inv, e1 * inv, e2 * inv, e3 * inv);
            }
            {
                const float mx  = fmaxf(fmaxf(v0.y, v1.y), fmaxf(v2.y, v3.y));
                const float e0  = __expf(v0.y - mx);
                const float e1  = __expf(v1.y - mx);
                const float e2  = __expf(v2.y - mx);
                const float e3  = __expf(v3.y - mx);
                const float inv = 1.0f / (e0 + e1 + e2 + e3);
                u1 = make_float4(e0 * inv, e1 * inv, e2 * inv, e3 * inv);
            }
        }
        u_lds[lr][lc]     = u0;
        u_lds[lr][lc + 1] = u1;
        *reinterpret_cast<float2*>(&m_lds[lr][lc]) = mm;
    }
    __syncthreads();

    // ---- fixed thread -> pixel-pair mapping over the step-1 region ----
    const int  p   = tid;                    // pair id (0..431 active)
    const int  lr1 = p / GPR1;               // region row
    const int  lc1 = 2 * (p - lr1 * GPR1);   // region col of first pixel (even)
    const int  gh  = h0 + lr1 - 2;
    const int  gw  = w0 + lc1 - 4;
    const bool inb = (p < NPAIR1) && gh >= 0 && gh < HH && gw >= 0 && gw < WW;

    // ---- filt taps loaded ONCE (post-barrier: do NOT move earlier) ----
    float2 f[14];
    if (inb) {
        const float* fp = filt + ((size_t)b * 14 * HH + gh) * WW + gw;
#pragma unroll
        for (int k = 0; k < 14; ++k)
            f[k] = *reinterpret_cast<const float2*>(fp + (size_t)k * PLANE);
    }

    // ---- fold mask into filt: fm[k] = f[k] * m_neighbor (step-invariant) ----
    float mcen0 = 0.f, mcen1 = 0.f;
    if (inb) {
        const int ur = lr1 + 1;
        const int uc = lc1 + 2;
        mcen0 = m_lds[ur][uc];
        mcen1 = m_lds[ur][uc + 1];
#pragma unroll
        for (int dz = -1; dz <= 1; ++dz) {
            const int rr = ur + dz;
            float M[6];
#pragma unroll
            for (int t3 = 0; t3 < 3; ++t3) {
                const float2 mm =
                    *reinterpret_cast<const float2*>(&m_lds[rr][uc - 2 + 2 * t3]);
                M[2 * t3]     = mm.x;
                M[2 * t3 + 1] = mm.y;
            }
#pragma unroll
            for (int t = 0; t < 5; ++t) {
                if (dz == 0 && t == 2) continue;
                const int k = (dz == -1) ? t
                            : (dz == 0)  ? 5 + (t > 2 ? t - 1 : t)
                                         : 9 + t;
                f[k].x *= M[t];
                f[k].y *= M[t + 1];
            }
        }
    }

    crf_step<2, 4, false>(u_lds, f, mcen0, mcen1, xout, b, lr1, lc1, gh, gw, inb);
    crf_step<1, 2, false>(u_lds, f, mcen0, mcen1, xout, b, lr1, lc1, gh, gw, inb);
    crf_step<0, 0, true >(u_lds, f, mcen0, mcen1, xout, b, lr1, lc1, gh, gw, inb);
}

extern "C" void kernel_launch(void* const* d_in, const int* in_sizes, int n_in,
                              void* d_out, int out_size, void* d_ws, size_t ws_size,
                              hipStream_t stream) {
    const float* x    = (const float*)d_in[0];  // [16,4,64,512]
    const float* filt = (const float*)d_in[1];  // [16,1,14,64,512]
    const float* msk  = (const float*)d_in[2];  // [16,1,64,512]
    float* out = (float*)d_out;
    (void)d_ws; (void)ws_size;

    dim3 grid(WW / TW, HH / TH, BB);   // (8, 8, 16) = 1024 blocks
    dim3 block(512);
    crf_fused<<<grid, block, 0, stream>>>(x, filt, msk, out);
}

// Round 6
// 95.927 us; speedup vs baseline: 1.1078x; 1.0949x over previous
//
#include <hip/hip_runtime.h>

// SqueezeSeg recurrent CRF, MI355X (gfx950). Single-kernel halo-redundant fusion,
// 3 CRF iterations per block over nested shrinking regions (12x72 -> 10x68 ->
// 8x64 around the owned 8x64 tile). Fixed thread->pixel-pair mapping (512-thread
// blocks, one pass per step). Structure = round-3 (96.1us) step schedule:
//  - filt loads post-barrier; step-1's A-side (no f dependence) overlaps the
//    in-flight filt burst. (r4/r5 regression: a separate fold phase consumed all
//    f[k] immediately -> serialized the fetch. Do not reintroduce it.)
//  - NEW (only delta vs r3): fm = f*mask products computed inline in step 1 are
//    PERSISTED into the f registers; steps 2-3 skip mask LDS reads and f*m muls.
// g_ang == g_bi (theta=0.9 both) -> ang == bi_ang.
// compat = (1-I)*coef -> out[o] = coef*(sum_c v[c] - v[o]).

#define NCLASS 4
#define HH 64
#define WW 512
#define BB 16
#define TH 8
#define TW 64
#define UR (TH + 6)     // 14 rows:  tile + 3 halo each side
#define UC (TW + 12)    // 76 cols:  tile + 6 halo each side
#define PLANE (HH * WW)
#define R1H 12          // step-1 region rows
#define R1W 72          // step-1 region cols
#define GPR1 (R1W / 2)  // 36 pixel-pairs per region row
#define NPAIR1 (R1H * GPR1)  // 432 pairs, one per thread

// exp(-d2 / (2*0.9^2)) for d2 = 1,2,4,5
#define G1 0.53940412f
#define G2 0.29095687f
#define G4 0.08466190f
#define G5 0.04566227f

__device__ __forceinline__ void fma4(float4& d, float s, const float4& v) {
    d.x = fmaf(s, v.x, d.x);
    d.y = fmaf(s, v.y, d.y);
    d.z = fmaf(s, v.z, d.z);
    d.w = fmaf(s, v.w, d.w);
}

// combine ang/bilateral accumulators into the new x (optionally softmaxed)
template <bool SM>
__device__ __forceinline__ float4 crf_combine(const float4 A, const float4 C,
                                              const float4 u, const float mcen)
{
    const float bx = C.x * mcen * A.x;
    const float by = C.y * mcen * A.y;
    const float bz = C.z * mcen * A.z;
    const float bw = C.w * mcen * A.w;
    const float sa = A.x + A.y + A.z + A.w;
    const float sb = bx + by + bz + bw;
    float4 r;
    r.x = u.x + 0.02f * (sa - A.x) + 0.1f * (sb - bx);
    r.y = u.y + 0.02f * (sa - A.y) + 0.1f * (sb - by);
    r.z = u.z + 0.02f * (sa - A.z) + 0.1f * (sb - bz);
    r.w = u.w + 0.02f * (sa - A.w) + 0.1f * (sb - bw);
    if (SM) {
        const float mx  = fmaxf(fmaxf(r.x, r.y), fmaxf(r.z, r.w));
        const float e0  = __expf(r.x - mx);
        const float e1  = __expf(r.y - mx);
        const float e2  = __expf(r.z - mx);
        const float e3  = __expf(r.w - mx);
        const float inv = 1.0f / (e0 + e1 + e2 + e3);
        r = make_float4(e0 * inv, e1 * inv, e2 * inv, e3 * inv);
    }
    return r;
}

// One CRF step for this thread's FIXED pixel pair.
// FIRST: fm[] holds raw filt taps; read mask from LDS, compute fm=f*m inline
//        (exactly the r3 schedule) and PERSIST the products + mcen for later.
// !FIRST: fm[] holds folded products; no mask reads, no muls.
// MR/MC: halo margin of the region this step computes. FINAL: global write.
template <int MR, int MC, bool FIRST, bool FINAL>
__device__ __forceinline__ void crf_step(
    float4 (*__restrict__ u_lds)[UC], const float (*__restrict__ m_lds)[UC],
    float2* __restrict__ fm, float& mcen0, float& mcen1,
    float* __restrict__ dst,
    int b, int lr1, int lc1, int gh, int gw, bool inb)
{
    constexpr int RH = TH + 2 * MR;
    constexpr int RW = TW + 2 * MC;
    // this step's region, expressed in step-1 coordinates (nested subsets)
    constexpr int LR_LO = 2 - MR, LR_HI = 2 - MR + RH;
    constexpr int LC_LO = 4 - MC, LC_HI = 4 - MC + RW;

    const bool act = inb && lr1 >= LR_LO && lr1 < LR_HI
                         && lc1 >= LC_LO && (lc1 + 1) < LC_HI;

    // Gaussian weights per tap column (t = da+2); edge rows vs center row
    const float GE[5] = {G5, G2, G1, G2, G5};
    const float GC[5] = {G4, G1, 0.f, G1, G4};

    float4 r0 = make_float4(0.f, 0.f, 0.f, 0.f);
    float4 r1 = r0;

    if (act) {
        const int ur = lr1 + 1;   // u_lds row of this pair
        const int uc = lc1 + 2;   // u_lds col of first pixel (even)

        float4 A0 = make_float4(0.f, 0.f, 0.f, 0.f);
        float4 A1 = A0, C0 = A0, C1 = A0;
        float4 ucen0 = A0, ucen1 = A0;

#pragma unroll
        for (int dz = -1; dz <= 1; ++dz) {
            const int rr = ur + dz;
            // 6-wide shared window: cols uc-2 .. uc+3 (uc even -> aligned)
            float4 U[6];
            float  M[6];
#pragma unroll
            for (int t = 0; t < 6; ++t) U[t] = u_lds[rr][uc - 2 + t];
            if (FIRST) {
#pragma unroll
                for (int t = 0; t < 3; ++t) {
                    const float2 mm =
                        *reinterpret_cast<const float2*>(&m_lds[rr][uc - 2 + 2 * t]);
                    M[2 * t]     = mm.x;
                    M[2 * t + 1] = mm.y;
                }
            }
            if (dz == 0) {
                ucen0 = U[2]; ucen1 = U[3];
                if (FIRST) { mcen0 = M[2]; mcen1 = M[3]; }
            }
#pragma unroll
            for (int t = 0; t < 5; ++t) {
                if (dz == 0 && t == 2) continue;   // center excluded
                const int   k  = (dz == -1) ? t
                               : (dz == 0)  ? 5 + (t > 2 ? t - 1 : t)
                                            : 9 + t;
                const float gk = (dz == 0) ? GC[t] : GE[t];
                float fm0, fm1;
                if (FIRST) {
                    fm0 = fm[k].x * M[t];
                    fm1 = fm[k].y * M[t + 1];
                    fm[k].x = fm0;           // persist folded product
                    fm[k].y = fm1;
                } else {
                    fm0 = fm[k].x;
                    fm1 = fm[k].y;
                }
                fma4(A0, gk,  U[t]);      fma4(C0, fm0, U[t]);
                fma4(A1, gk,  U[t + 1]);  fma4(C1, fm1, U[t + 1]);
            }
        }
        r0 = crf_combine<!FINAL>(A0, C0, ucen0, mcen0);
        r1 = crf_combine<!FINAL>(A1, C1, ucen1, mcen1);

        if (FINAL) {
            float* o = dst + ((size_t)b * NCLASS * HH + gh) * WW + gw;
            *reinterpret_cast<float2*>(o)             = make_float2(r0.x, r1.x);
            *reinterpret_cast<float2*>(o + PLANE)     = make_float2(r0.y, r1.y);
            *reinterpret_cast<float2*>(o + 2 * PLANE) = make_float2(r0.z, r1.z);
            *reinterpret_cast<float2*>(o + 3 * PLANE) = make_float2(r0.w, r1.w);
        }
    }

    if (!FINAL) {
        __syncthreads();   // all reads of u_t done before overwrite
        if (act) {
            u_lds[lr1 + 1][lc1 + 2] = r0;
            u_lds[lr1 + 1][lc1 + 3] = r1;
        }
        // global-OOB entries inside the region were 0 from phase 0 and are
        // never rewritten -> stay 0, matching zero-pad gather semantics.
        __syncthreads();   // u_{t+1} visible before next step's reads
    }
}

__global__ __launch_bounds__(512, 4) void crf_fused(
    const float* __restrict__ xin,   // [B,4,H,W]
    const float* __restrict__ filt,  // [B,1,14,H,W]
    const float* __restrict__ mask,  // [B,1,H,W]
    float* __restrict__ xout)        // [B,4,H,W]
{
    __shared__ float4 u_lds[UR][UC];  // class-packed unary, 17.0 KB
    __shared__ float  m_lds[UR][UC];  // mask, 4.3 KB

    const int b   = blockIdx.z;
    const int h0  = blockIdx.y * TH;
    const int w0  = blockIdx.x * TW;
    const int tid = threadIdx.x;

    // ---- phase 0: softmax(x) + mask over the full 14x76 patch, pixel pairs ----
    constexpr int NP = (UR * UC) / 2;   // 532 pairs
    for (int idx = tid; idx < NP; idx += 512) {
        const int lr = idx / (UC / 2);
        const int lc = 2 * (idx - lr * (UC / 2));
        const int ph = h0 + lr - 3;
        const int pw = w0 + lc - 6;     // even -> pair never straddles 0/W
        float4 u0 = make_float4(0.f, 0.f, 0.f, 0.f);
        float4 u1 = u0;
        float2 mm = make_float2(0.f, 0.f);
        if (ph >= 0 && ph < HH && pw >= 0 && pw < WW) {
            const float* px = xin + ((size_t)b * NCLASS * HH + ph) * WW + pw;
            const float2 v0 = *reinterpret_cast<const float2*>(px);
            const float2 v1 = *reinterpret_cast<const float2*>(px + PLANE);
            const float2 v2 = *reinterpret_cast<const float2*>(px + 2 * PLANE);
            const float2 v3 = *reinterpret_cast<const float2*>(px + 3 * PLANE);
            mm = *reinterpret_cast<const float2*>(mask + ((size_t)b * HH + ph) * WW + pw);
            {
                const float mx  = fmaxf(fmaxf(v0.x, v1.x), fmaxf(v2.x, v3.x));
                const float e0  = __expf(v0.x - mx);
                const float e1  = __expf(v1.x - mx);
                const float e2  = __expf(v2.x - mx);
                const float e3  = __expf(v3.x - mx);
                const float inv = 1.0f / (e0 + e1 + e2 + e3);
                u0 = make_float4(e0 * inv, e1 * inv, e2 * inv, e3 * inv);
            }
            {
                const float mx  = fmaxf(fmaxf(v0.y, v1.y), fmaxf(v2.y, v3.y));
                const float e0  = __expf(v0.y - mx);
                const float e1  = __expf(v1.y - mx);
                const float e2  = __expf(v2.y - mx);
                const float e3  = __expf(v3.y - mx);
                const float inv = 1.0f / (e0 + e1 + e2 + e3);
                u1 = make_float4(e0 * inv, e1 * inv, e2 * inv, e3 * inv);
            }
        }
        u_lds[lr][lc]     = u0;
        u_lds[lr][lc + 1] = u1;
        *reinterpret_cast<float2*>(&m_lds[lr][lc]) = mm;
    }
    __syncthreads();

    // ---- fixed thread -> pixel-pair mapping over the step-1 region ----
    const int  p   = tid;                    // pair id (0..431 active)
    const int  lr1 = p / GPR1;               // region row
    const int  lc1 = 2 * (p - lr1 * GPR1);   // region col of first pixel (even)
    const int  gh  = h0 + lr1 - 2;
    const int  gw  = w0 + lc1 - 4;
    const bool inb = (p < NPAIR1) && gh >= 0 && gh < HH && gw >= 0 && gw < WW;

    // ---- filt taps loaded ONCE (post-barrier; step-1 A-side hides the wait) ----
    float2 f[14];
    if (inb) {
        const float* fp = filt + ((size_t)b * 14 * HH + gh) * WW + gw;
#pragma unroll
        for (int k = 0; k < 14; ++k)
            f[k] = *reinterpret_cast<const float2*>(fp + (size_t)k * PLANE);
    }

    float mcen0 = 0.f, mcen1 = 0.f;
    crf_step<2, 4, true,  false>(u_lds, m_lds, f, mcen0, mcen1, xout, b, lr1, lc1, gh, gw, inb);
    crf_step<1, 2, false, false>(u_lds, m_lds, f, mcen0, mcen1, xout, b, lr1, lc1, gh, gw, inb);
    crf_step<0, 0, false, true >(u_lds, m_lds, f, mcen0, mcen1, xout, b, lr1, lc1, gh, gw, inb);
}

extern "C" void kernel_launch(void* const* d_in, const int* in_sizes, int n_in,
                              void* d_out, int out_size, void* d_ws, size_t ws_size,
                              hipStream_t stream) {
    const float* x    = (const float*)d_in[0];  // [16,4,64,512]
    const float* filt = (const float*)d_in[1];  // [16,1,14,64,512]
    const float* msk  = (const float*)d_in[2];  // [16,1,64,512]
    float* out = (float*)d_out;
    (void)d_ws; (void)ws_size;

    dim3 grid(WW / TW, HH / TH, BB);   // (8, 8, 16) = 1024 blocks
    dim3 block(512);
    crf_fused<<<grid, block, 0, stream>>>(x, filt, msk, out);
}